// Round 1
// baseline (517.218 us; speedup 1.0000x reference)
//
#include <hip/hip_runtime.h>

#define NROWS 300000
#define NBLK ((NROWS + 63) / 64)

typedef float f32x4 __attribute__((ext_vector_type(4)));
typedef short s16x8 __attribute__((ext_vector_type(8)));
typedef unsigned short u16x8 __attribute__((ext_vector_type(8)));
typedef unsigned short u16x4 __attribute__((ext_vector_type(4)));

__device__ __forceinline__ float bf2f(unsigned short u) {
    return __uint_as_float(((unsigned)u) << 16);
}
__device__ __forceinline__ unsigned short f2bf(float f) {
    unsigned u = __float_as_uint(f);
    u += 0x7FFFu + ((u >> 16) & 1u);   // round-to-nearest-even
    return (unsigned short)(u >> 16);
}

// ---------------------------------------------------------------------------
// W prep: W[k][c][d] f32  ->  WT[k][d][c] bf16  (both convs)
// ---------------------------------------------------------------------------
__global__ __launch_bounds__(256) void w_prep(const float* __restrict__ W1,
                                              const float* __restrict__ W2,
                                              unsigned short* __restrict__ WT1,
                                              unsigned short* __restrict__ WT2) {
    const int i = blockIdx.x * 256 + threadIdx.x;
    if (i < 9 * 4096) {
        const int k = i >> 12, cc = (i >> 6) & 63, d = i & 63;
        const int o = k * 4096 + d * 64 + cc;
        WT1[o] = f2bf(W1[i]);
        WT2[o] = f2bf(W2[i]);
    }
}

// ---------------------------------------------------------------------------
// Gathered GEMM via MFMA 16x16x32 bf16.
// CONV==1: input = f32 x, no BN.  CONV==2: input = bf16, fold relu(v*s+b).
// Block = 4 waves; wave w computes rows [blk*64 + w*16, +16) x all 64 cols.
// A-frag: lane l holds G[row = l&15][k = (l>>4)*8 + j], gathered from global.
// B-frag: lane l holds W[c = (l>>4)*8+j][d = dj*16 + (l&15)] from WT[k][d][c].
// D-frag: lane l reg r -> row (l>>4)*4+r, col l&15.
// ---------------------------------------------------------------------------
template <int CONV>
__global__ __launch_bounds__(256) void conv_mfma(const float* __restrict__ xf,
                                                 const unsigned short* __restrict__ xb,
                                                 const int* __restrict__ nbrs,
                                                 const unsigned short* __restrict__ WT,
                                                 const float* __restrict__ sb,
                                                 unsigned short* __restrict__ outb) {
    const int tid = threadIdx.x;
    const int l = tid & 63;
    const int w = tid >> 6;
    const int lr = l & 15;
    const int kg = l >> 4;
    const int c00 = kg * 8;

    const int rowA = blockIdx.x * 64 + w * 16 + lr;
    const int rowAc = rowA < NROWS ? rowA : NROWS - 1;

    float sreg[2][8], breg[2][8];
    if (CONV == 2) {
#pragma unroll
        for (int ch = 0; ch < 2; ++ch)
#pragma unroll
            for (int j = 0; j < 8; ++j) {
                sreg[ch][j] = sb[ch * 32 + c00 + j];
                breg[ch][j] = sb[64 + ch * 32 + c00 + j];
            }
    }

    int nb[9];
#pragma unroll
    for (int k = 0; k < 9; ++k) nb[k] = nbrs[rowAc * 9 + k];

    f32x4 acc[4];
#pragma unroll
    for (int d = 0; d < 4; ++d) {
        acc[d][0] = 0.f; acc[d][1] = 0.f; acc[d][2] = 0.f; acc[d][3] = 0.f;
    }

#pragma unroll
    for (int k = 0; k < 9; ++k) {
#pragma unroll
        for (int ch = 0; ch < 2; ++ch) {
            const int c0 = ch * 32 + c00;
            s16x8 a;
            if (CONV == 1) {
                const float* rp = xf + (size_t)nb[k] * 64 + c0;
                const float4 v0 = *(const float4*)rp;
                const float4 v1 = *(const float4*)(rp + 4);
                a[0] = (short)f2bf(v0.x); a[1] = (short)f2bf(v0.y);
                a[2] = (short)f2bf(v0.z); a[3] = (short)f2bf(v0.w);
                a[4] = (short)f2bf(v1.x); a[5] = (short)f2bf(v1.y);
                a[6] = (short)f2bf(v1.z); a[7] = (short)f2bf(v1.w);
            } else {
                const u16x8 raw = *(const u16x8*)(xb + (size_t)nb[k] * 64 + c0);
#pragma unroll
                for (int j = 0; j < 8; ++j) {
                    float f = bf2f(raw[j]);
                    f = fmaxf(f * sreg[ch][j] + breg[ch][j], 0.f);
                    a[j] = (short)f2bf(f);
                }
            }
            const unsigned short* wp = WT + k * 4096 + lr * 64 + c0;
#pragma unroll
            for (int dj = 0; dj < 4; ++dj) {
                const s16x8 b = *(const s16x8*)(wp + dj * 1024);
                acc[dj] = __builtin_amdgcn_mfma_f32_16x16x32_bf16(a, b, acc[dj], 0, 0, 0);
            }
        }
    }

    const int orow0 = blockIdx.x * 64 + w * 16 + kg * 4;
#pragma unroll
    for (int dj = 0; dj < 4; ++dj) {
#pragma unroll
        for (int r = 0; r < 4; ++r) {
            const int orow = orow0 + r;
            if (orow < NROWS) outb[(size_t)orow * 64 + dj * 16 + lr] = f2bf(acc[dj][r]);
        }
    }
}

// ---------------------------------------------------------------------------
// Per-channel sum / sum-of-squares over all rows (bf16 input).
// S[0..63] = sum, S[64..127] = sumsq. Must be zeroed before launch.
// ---------------------------------------------------------------------------
__global__ __launch_bounds__(256) void bn_stats(const unsigned short* __restrict__ fb,
                                                float* __restrict__ S) {
    const int t = threadIdx.x;
    const int c4 = (t & 15) * 4;
    const int rg = t >> 4;
    float s0 = 0, s1 = 0, s2 = 0, s3 = 0, q0 = 0, q1 = 0, q2 = 0, q3 = 0;
    for (int r = blockIdx.x * 16 + rg; r < NROWS; r += gridDim.x * 16) {
        const u16x4 v = *(const u16x4*)(fb + (size_t)r * 64 + c4);
        const float f0 = bf2f(v[0]), f1 = bf2f(v[1]), f2 = bf2f(v[2]), f3 = bf2f(v[3]);
        s0 += f0; s1 += f1; s2 += f2; s3 += f3;
        q0 += f0 * f0; q1 += f1 * f1; q2 += f2 * f2; q3 += f3 * f3;
    }
    __shared__ float red[16][64];
    red[rg][c4 + 0] = s0; red[rg][c4 + 1] = s1; red[rg][c4 + 2] = s2; red[rg][c4 + 3] = s3;
    __syncthreads();
    if (t < 64) {
        float a = 0;
#pragma unroll
        for (int i = 0; i < 16; ++i) a += red[i][t];
        atomicAdd(&S[t], a);
    }
    __syncthreads();
    red[rg][c4 + 0] = q0; red[rg][c4 + 1] = q1; red[rg][c4 + 2] = q2; red[rg][c4 + 3] = q3;
    __syncthreads();
    if (t < 64) {
        float a = 0;
#pragma unroll
        for (int i = 0; i < 16; ++i) a += red[i][t];
        atomicAdd(&S[64 + t], a);
    }
}

// ---------------------------------------------------------------------------
// Fold BN stats into per-channel scale/shift: f = v*s + b
// ---------------------------------------------------------------------------
__global__ void bn_finalize(const float* __restrict__ S, const float* __restrict__ gamma,
                            const float* __restrict__ beta, float* __restrict__ sb) {
    const int c = threadIdx.x;
    if (c < 64) {
        const float mean = S[c] * (1.0f / NROWS);
        const float var = S[64 + c] * (1.0f / NROWS) - mean * mean;
        const float sc = gamma[c] * rsqrtf(var + 1e-5f);
        sb[c] = sc;
        sb[64 + c] = beta[c] - mean * sc;
    }
}

// ---------------------------------------------------------------------------
// out = relu(out2*s2 + b2 + x), f32 output
// ---------------------------------------------------------------------------
__global__ __launch_bounds__(256) void final_out(const unsigned short* __restrict__ o2,
                                                 const float* __restrict__ x,
                                                 const float* __restrict__ sb,
                                                 float* __restrict__ out) {
    const int NQ = NROWS * 16;
    for (int i = blockIdx.x * 256 + threadIdx.x; i < NQ; i += gridDim.x * 256) {
        const int c4 = (i & 15) * 4;
        const u16x4 v = *(const u16x4*)(o2 + (size_t)i * 4);
        const float4 xv = *(const float4*)(x + (size_t)i * 4);
        const float4 s = *(const float4*)(sb + c4);
        const float4 b = *(const float4*)(sb + 64 + c4);
        float4 o;
        o.x = fmaxf(bf2f(v[0]) * s.x + b.x + xv.x, 0.f);
        o.y = fmaxf(bf2f(v[1]) * s.y + b.y + xv.y, 0.f);
        o.z = fmaxf(bf2f(v[2]) * s.z + b.z + xv.z, 0.f);
        o.w = fmaxf(bf2f(v[3]) * s.w + b.w + xv.w, 0.f);
        *(float4*)(out + (size_t)i * 4) = o;
    }
}

extern "C" void kernel_launch(void* const* d_in, const int* in_sizes, int n_in,
                              void* d_out, int out_size, void* d_ws, size_t ws_size,
                              hipStream_t stream) {
    const float* x      = (const float*)d_in[0];
    const int*   nbrs   = (const int*)d_in[1];
    const float* W1     = (const float*)d_in[2];
    const float* gamma1 = (const float*)d_in[3];
    const float* beta1  = (const float*)d_in[4];
    const float* W2     = (const float*)d_in[5];
    const float* gamma2 = (const float*)d_in[6];
    const float* beta2  = (const float*)d_in[7];
    float* out = (float*)d_out;

    // ws layout (~38.6 MB): out2 bf16 | WT1 | WT2 | stats
    char* ws = (char*)d_ws;
    unsigned short* out2b = (unsigned short*)ws;                       // 38,400,000 B
    unsigned short* WT1   = (unsigned short*)(ws + 38400000);          // 73,728 B
    unsigned short* WT2   = (unsigned short*)(ws + 38400000 + 73728);  // 73,728 B
    float* Sa  = (float*)(ws + 38400000 + 147456);                     // 128 f32
    float* Sb  = Sa + 128;
    float* sb1 = Sa + 256;
    float* sb2 = Sa + 384;
    // out1 (bf16) scratch lives in d_out's front half; final_out overwrites all of d_out.
    unsigned short* out1b = (unsigned short*)d_out;

    hipMemsetAsync(Sa, 0, 256 * sizeof(float), stream);
    w_prep<<<144, 256, 0, stream>>>(W1, W2, WT1, WT2);
    conv_mfma<1><<<NBLK, 256, 0, stream>>>(x, nullptr, nbrs, WT1, nullptr, out1b);
    bn_stats<<<512, 256, 0, stream>>>(out1b, Sa);
    bn_finalize<<<1, 64, 0, stream>>>(Sa, gamma1, beta1, sb1);
    conv_mfma<2><<<NBLK, 256, 0, stream>>>(nullptr, out1b, nbrs, WT2, sb1, out2b);
    bn_stats<<<512, 256, 0, stream>>>(out2b, Sb);
    bn_finalize<<<1, 64, 0, stream>>>(Sb, gamma2, beta2, sb2);
    final_out<<<2048, 256, 0, stream>>>(out2b, x, sb2, out);
}

// Round 2
// 504.717 us; speedup vs baseline: 1.0248x; 1.0248x over previous
//
#include <hip/hip_runtime.h>

#define NROWS 300000
#define NBLK ((NROWS + 63) / 64)

typedef float f32x4 __attribute__((ext_vector_type(4)));
typedef short s16x8 __attribute__((ext_vector_type(8)));
typedef unsigned short u16x8 __attribute__((ext_vector_type(8)));
typedef unsigned short u16x4 __attribute__((ext_vector_type(4)));

__device__ __forceinline__ float bf2f(unsigned short u) {
    return __uint_as_float(((unsigned)u) << 16);
}
__device__ __forceinline__ unsigned short f2bf(float f) {
    unsigned u = __float_as_uint(f);
    u += 0x7FFFu + ((u >> 16) & 1u);   // round-to-nearest-even
    return (unsigned short)(u >> 16);
}

// ---------------------------------------------------------------------------
// x (f32, N x 64) -> xb (bf16), vectorized 8/thread
// ---------------------------------------------------------------------------
__global__ __launch_bounds__(256) void x2bf(const float* __restrict__ x,
                                            unsigned short* __restrict__ xb) {
    const int NQ = NROWS * 8;
    for (int i = blockIdx.x * 256 + threadIdx.x; i < NQ; i += gridDim.x * 256) {
        const float4 v0 = *(const float4*)(x + (size_t)i * 8);
        const float4 v1 = *(const float4*)(x + (size_t)i * 8 + 4);
        u16x8 o;
        o[0] = f2bf(v0.x); o[1] = f2bf(v0.y); o[2] = f2bf(v0.z); o[3] = f2bf(v0.w);
        o[4] = f2bf(v1.x); o[5] = f2bf(v1.y); o[6] = f2bf(v1.z); o[7] = f2bf(v1.w);
        *(u16x8*)(xb + (size_t)i * 8) = o;
    }
}

// ---------------------------------------------------------------------------
// W prep: W[k][c][d] f32  ->  WT[k][d][c] bf16  (both convs)
// ---------------------------------------------------------------------------
__global__ __launch_bounds__(256) void w_prep(const float* __restrict__ W1,
                                              const float* __restrict__ W2,
                                              unsigned short* __restrict__ WT1,
                                              unsigned short* __restrict__ WT2) {
    const int i = blockIdx.x * 256 + threadIdx.x;
    if (i < 9 * 4096) {
        const int k = i >> 12, cc = (i >> 6) & 63, d = i & 63;
        const int o = k * 4096 + d * 64 + cc;
        WT1[o] = f2bf(W1[i]);
        WT2[o] = f2bf(W2[i]);
    }
}

// ---------------------------------------------------------------------------
// Gathered GEMM via MFMA 16x16x32 bf16, bf16 input, no fused BN.
// Block = 4 waves; wave w computes rows [blk*64 + w*16, +16) x all 64 cols.
// A-frag: lane l holds G[row = l&15][c = ch*32 + (l>>4)*8 + j], gathered.
// All 18 gather loads are staged into registers BEFORE the MFMA loop so they
// are all in flight concurrently (memory-level parallelism).
// B-frag: lane l holds W[c][d = dj*16 + (l&15)] from WT[k][d][c].
// D-frag: lane l reg r -> row (l>>4)*4+r, col dj*16 + (l&15).
// ---------------------------------------------------------------------------
__global__ __launch_bounds__(256) void conv_mfma(const unsigned short* __restrict__ xb,
                                                 const int* __restrict__ nbrs,
                                                 const unsigned short* __restrict__ WT,
                                                 unsigned short* __restrict__ outb) {
    const int tid = threadIdx.x;
    const int l = tid & 63;
    const int w = tid >> 6;
    const int lr = l & 15;
    const int kg = l >> 4;
    const int c00 = kg * 8;

    const int rowA = blockIdx.x * 64 + w * 16 + lr;
    const int rowAc = rowA < NROWS ? rowA : NROWS - 1;

    int nb[9];
#pragma unroll
    for (int k = 0; k < 9; ++k) nb[k] = nbrs[rowAc * 9 + k];

    // Stage ALL gathers first: 18 independent 16-B loads in flight per lane.
    s16x8 raw0[9], raw1[9];
#pragma unroll
    for (int k = 0; k < 9; ++k) {
        const unsigned short* rp = xb + (size_t)nb[k] * 64 + c00;
        raw0[k] = *(const s16x8*)rp;        // channels [c00, c00+8)
        raw1[k] = *(const s16x8*)(rp + 32); // channels [c00+32, c00+40)
    }

    f32x4 acc[4];
#pragma unroll
    for (int d = 0; d < 4; ++d) {
        acc[d][0] = 0.f; acc[d][1] = 0.f; acc[d][2] = 0.f; acc[d][3] = 0.f;
    }

#pragma unroll
    for (int k = 0; k < 9; ++k) {
        const unsigned short* wp = WT + k * 4096 + lr * 64 + c00;
#pragma unroll
        for (int dj = 0; dj < 4; ++dj) {
            const s16x8 b0 = *(const s16x8*)(wp + dj * 1024);        // ch 0..31 slice
            const s16x8 b1 = *(const s16x8*)(wp + dj * 1024 + 32);   // ch 32..63 slice
            acc[dj] = __builtin_amdgcn_mfma_f32_16x16x32_bf16(raw0[k], b0, acc[dj], 0, 0, 0);
            acc[dj] = __builtin_amdgcn_mfma_f32_16x16x32_bf16(raw1[k], b1, acc[dj], 0, 0, 0);
        }
    }

    const int orow0 = blockIdx.x * 64 + w * 16 + kg * 4;
#pragma unroll
    for (int dj = 0; dj < 4; ++dj) {
#pragma unroll
        for (int r = 0; r < 4; ++r) {
            const int orow = orow0 + r;
            if (orow < NROWS) outb[(size_t)orow * 64 + dj * 16 + lr] = f2bf(acc[dj][r]);
        }
    }
}

// ---------------------------------------------------------------------------
// Per-channel sum / sum-of-squares over all rows (bf16 input).
// S[0..63] = sum, S[64..127] = sumsq. Must be zeroed before launch.
// ---------------------------------------------------------------------------
__global__ __launch_bounds__(256) void bn_stats(const unsigned short* __restrict__ fb,
                                                float* __restrict__ S) {
    const int t = threadIdx.x;
    const int c4 = (t & 15) * 4;
    const int rg = t >> 4;
    float s0 = 0, s1 = 0, s2 = 0, s3 = 0, q0 = 0, q1 = 0, q2 = 0, q3 = 0;
    for (int r = blockIdx.x * 16 + rg; r < NROWS; r += gridDim.x * 16) {
        const u16x4 v = *(const u16x4*)(fb + (size_t)r * 64 + c4);
        const float f0 = bf2f(v[0]), f1 = bf2f(v[1]), f2 = bf2f(v[2]), f3 = bf2f(v[3]);
        s0 += f0; s1 += f1; s2 += f2; s3 += f3;
        q0 += f0 * f0; q1 += f1 * f1; q2 += f2 * f2; q3 += f3 * f3;
    }
    __shared__ float red[16][64];
    red[rg][c4 + 0] = s0; red[rg][c4 + 1] = s1; red[rg][c4 + 2] = s2; red[rg][c4 + 3] = s3;
    __syncthreads();
    if (t < 64) {
        float a = 0;
#pragma unroll
        for (int i = 0; i < 16; ++i) a += red[i][t];
        atomicAdd(&S[t], a);
    }
    __syncthreads();
    red[rg][c4 + 0] = q0; red[rg][c4 + 1] = q1; red[rg][c4 + 2] = q2; red[rg][c4 + 3] = q3;
    __syncthreads();
    if (t < 64) {
        float a = 0;
#pragma unroll
        for (int i = 0; i < 16; ++i) a += red[i][t];
        atomicAdd(&S[64 + t], a);
    }
}

// ---------------------------------------------------------------------------
// Fold BN stats into per-channel scale/shift: f = v*s + b
// ---------------------------------------------------------------------------
__global__ void bn_finalize(const float* __restrict__ S, const float* __restrict__ gamma,
                            const float* __restrict__ beta, float* __restrict__ sb) {
    const int c = threadIdx.x;
    if (c < 64) {
        const float mean = S[c] * (1.0f / NROWS);
        const float var = S[64 + c] * (1.0f / NROWS) - mean * mean;
        const float sc = gamma[c] * rsqrtf(var + 1e-5f);
        sb[c] = sc;
        sb[64 + c] = beta[c] - mean * sc;
    }
}

// ---------------------------------------------------------------------------
// In-place BN1 + ReLU on bf16 feature map: f = relu(f*s + b)
// ---------------------------------------------------------------------------
__global__ __launch_bounds__(256) void bn_apply(unsigned short* __restrict__ fb,
                                                const float* __restrict__ sb) {
    const int NQ = NROWS * 8;
    for (int i = blockIdx.x * 256 + threadIdx.x; i < NQ; i += gridDim.x * 256) {
        const int c8 = (i & 7) * 8;
        u16x8 v = *(const u16x8*)(fb + (size_t)i * 8);
        u16x8 o;
#pragma unroll
        for (int j = 0; j < 8; ++j) {
            const float f = fmaxf(bf2f(v[j]) * sb[c8 + j] + sb[64 + c8 + j], 0.f);
            o[j] = f2bf(f);
        }
        *(u16x8*)(fb + (size_t)i * 8) = o;
    }
}

// ---------------------------------------------------------------------------
// out = relu(out2*s2 + b2 + x), f32 output
// ---------------------------------------------------------------------------
__global__ __launch_bounds__(256) void final_out(const unsigned short* __restrict__ o2,
                                                 const float* __restrict__ x,
                                                 const float* __restrict__ sb,
                                                 float* __restrict__ out) {
    const int NQ = NROWS * 16;
    for (int i = blockIdx.x * 256 + threadIdx.x; i < NQ; i += gridDim.x * 256) {
        const int c4 = (i & 15) * 4;
        const u16x4 v = *(const u16x4*)(o2 + (size_t)i * 4);
        const float4 xv = *(const float4*)(x + (size_t)i * 4);
        const float4 s = *(const float4*)(sb + c4);
        const float4 b = *(const float4*)(sb + 64 + c4);
        float4 o;
        o.x = fmaxf(bf2f(v[0]) * s.x + b.x + xv.x, 0.f);
        o.y = fmaxf(bf2f(v[1]) * s.y + b.y + xv.y, 0.f);
        o.z = fmaxf(bf2f(v[2]) * s.z + b.z + xv.z, 0.f);
        o.w = fmaxf(bf2f(v[3]) * s.w + b.w + xv.w, 0.f);
        *(float4*)(out + (size_t)i * 4) = o;
    }
}

extern "C" void kernel_launch(void* const* d_in, const int* in_sizes, int n_in,
                              void* d_out, int out_size, void* d_ws, size_t ws_size,
                              hipStream_t stream) {
    const float* x      = (const float*)d_in[0];
    const int*   nbrs   = (const int*)d_in[1];
    const float* W1     = (const float*)d_in[2];
    const float* gamma1 = (const float*)d_in[3];
    const float* beta1  = (const float*)d_in[4];
    const float* W2     = (const float*)d_in[5];
    const float* gamma2 = (const float*)d_in[6];
    const float* beta2  = (const float*)d_in[7];
    float* out = (float*)d_out;

    // ws layout (~38.6 MB): out2 bf16 | WT1 | WT2 | stats
    char* ws = (char*)d_ws;
    unsigned short* out2b = (unsigned short*)ws;                       // 38,400,000 B
    unsigned short* WT1   = (unsigned short*)(ws + 38400000);          // 73,728 B
    unsigned short* WT2   = (unsigned short*)(ws + 38400000 + 73728);  // 73,728 B
    float* Sa  = (float*)(ws + 38400000 + 147456);                     // 128 f32
    float* Sb  = Sa + 128;
    float* sb1 = Sa + 256;
    float* sb2 = Sa + 384;
    // d_out doubles as scratch until final_out rewrites it:
    //   front half: out1b (bf16, 38.4 MB), back half: xb (bf16, 38.4 MB)
    unsigned short* out1b = (unsigned short*)d_out;
    unsigned short* xb    = (unsigned short*)d_out + 19200000;

    hipMemsetAsync(Sa, 0, 256 * sizeof(float), stream);
    x2bf<<<2048, 256, 0, stream>>>(x, xb);
    w_prep<<<144, 256, 0, stream>>>(W1, W2, WT1, WT2);
    conv_mfma<<<NBLK, 256, 0, stream>>>(xb, nbrs, WT1, out1b);
    bn_stats<<<512, 256, 0, stream>>>(out1b, Sa);
    bn_finalize<<<1, 64, 0, stream>>>(Sa, gamma1, beta1, sb1);
    bn_apply<<<2048, 256, 0, stream>>>(out1b, sb1);
    conv_mfma<<<NBLK, 256, 0, stream>>>(out1b, nbrs, WT2, out2b);
    bn_stats<<<512, 256, 0, stream>>>(out2b, Sb);
    bn_finalize<<<1, 64, 0, stream>>>(Sb, gamma2, beta2, sb2);
    final_out<<<2048, 256, 0, stream>>>(out2b, x, sb2, out);
}